// Round 5
// baseline (159.912 us; speedup 1.0000x reference)
//
#include <hip/hip_runtime.h>

// y[n,c,h,w] = x[n,c,h,w] * w[c] + b[c]
// x: (32, 64, 224, 224) fp32. One workgroup per (n,c) plane.
// Plane = 50176 floats = 12544 float4 = 49 * 256.
// Depth-8 load batches (proven best, r3). NT on LOADS only (streaming reads,
// keep them out of L2); NORMAL stores (let L2 coalesce the write stream into
// efficient HBM bursts — the write-only fill at 6.9 TB/s uses normal stores).

typedef float f32x4 __attribute__((ext_vector_type(4)));

__global__ __launch_bounds__(256) void scale_kernel(
    const f32x4* __restrict__ x,
    const float* __restrict__ w,
    const float* __restrict__ b,
    f32x4*       __restrict__ y) {
    const int plane = blockIdx.x;          // 0..2047  (= n*64 + c)
    const int c = plane & 63;
    const float wc = w[c];
    const float bc = b[c];

    const long long base = (long long)plane * 12544;
    const f32x4* __restrict__ xp = x + base;
    f32x4*       __restrict__ yp = y + base;
    const int tid = threadIdx.x;

    for (int bi = 0; bi < 6; ++bi) {
        const int o = bi * 2048 + tid;     // 8*256 = 2048 vec per batch
        f32x4 v[8];
        #pragma unroll
        for (int j = 0; j < 8; ++j)
            v[j] = __builtin_nontemporal_load(&xp[o + j * 256]);
        #pragma unroll
        for (int j = 0; j < 8; ++j) {
            f32x4 t = v[j];
            t.x = fmaf(t.x, wc, bc);
            t.y = fmaf(t.y, wc, bc);
            t.z = fmaf(t.z, wc, bc);
            t.w = fmaf(t.w, wc, bc);
            yp[o + j * 256] = t;           // normal (cached) store
        }
    }
    {   // tail iteration 49 = 6*8 + 1
        const int o = 12288 + tid;
        f32x4 t = __builtin_nontemporal_load(&xp[o]);
        t.x = fmaf(t.x, wc, bc);
        t.y = fmaf(t.y, wc, bc);
        t.z = fmaf(t.z, wc, bc);
        t.w = fmaf(t.w, wc, bc);
        yp[o] = t;
    }
}

extern "C" void kernel_launch(void* const* d_in, const int* in_sizes, int n_in,
                              void* d_out, int out_size, void* d_ws, size_t ws_size,
                              hipStream_t stream) {
    const float* x = (const float*)d_in[0];
    const float* w = (const float*)d_in[1];
    const float* b = (const float*)d_in[2];
    float* y = (float*)d_out;

    const int planes = 32 * 64;  // 2048 workgroups
    scale_kernel<<<planes, 256, 0, stream>>>(
        (const f32x4*)x, w, b, (f32x4*)y);
}

// Round 6
// 151.851 us; speedup vs baseline: 1.0531x; 1.0531x over previous
//
#include <hip/hip_runtime.h>

// y[n,c,h,w] = x[n,c,h,w] * w[c] + b[c]
// x: (32, 64, 224, 224) fp32. One workgroup per (n,c) plane.
// Plane = 50176 floats = 12544 float4 = 49 * 256 = 6 batches of 8 + 1 tail.
// r3-best config (depth-8, NT loads AND NT stores) + explicit 2-stage
// software pipeline: issue batch i+1's loads BEFORE storing batch i, so the
// read stream stays busy through the store phase (loads/stores share the
// in-order vmcnt queue; the naive order drains it at every batch boundary).
// va/vb named arrays with static indices only (runtime-indexed ext_vector
// arrays spill to scratch).

typedef float f32x4 __attribute__((ext_vector_type(4)));

#define LOAD8(dst, off)                                            \
    _Pragma("unroll")                                              \
    for (int j = 0; j < 8; ++j)                                    \
        dst[j] = __builtin_nontemporal_load(&xp[(off) + j * 256]);

#define STORE8(src, off)                                           \
    _Pragma("unroll")                                              \
    for (int j = 0; j < 8; ++j) {                                  \
        f32x4 t = src[j];                                          \
        t.x = fmaf(t.x, wc, bc);                                   \
        t.y = fmaf(t.y, wc, bc);                                   \
        t.z = fmaf(t.z, wc, bc);                                   \
        t.w = fmaf(t.w, wc, bc);                                   \
        __builtin_nontemporal_store(t, &yp[(off) + j * 256]);      \
    }

__global__ __launch_bounds__(256) void scale_kernel(
    const f32x4* __restrict__ x,
    const float* __restrict__ w,
    const float* __restrict__ b,
    f32x4*       __restrict__ y) {
    const int plane = blockIdx.x;          // 0..2047  (= n*64 + c)
    const int c = plane & 63;
    const float wc = w[c];
    const float bc = b[c];

    const long long base = (long long)plane * 12544;
    const f32x4* __restrict__ xp = x + base;
    f32x4*       __restrict__ yp = y + base;
    const int tid = threadIdx.x;

    f32x4 va[8], vb[8];

    // prologue: batch 0 in flight
    LOAD8(va, tid);

    // batches: 0..5, each 2048 vecs apart; pipeline 2-deep, unrolled x2
    #pragma unroll
    for (int bi = 0; bi < 2; ++bi) {
        const int o = bi * 4096 + tid;
        LOAD8(vb, o + 2048);               // loads batch 2bi+1
        STORE8(va, o);                     // stores batch 2bi
        LOAD8(va, o + 4096);               // loads batch 2bi+2
        STORE8(vb, o + 2048);              // stores batch 2bi+1
    }
    // va holds batch 4
    LOAD8(vb, 10240 + tid);                // batch 5
    STORE8(va, 8192 + tid);                // batch 4
    // tail load before final store phase
    f32x4 t49 = __builtin_nontemporal_load(&xp[12288 + tid]);
    STORE8(vb, 10240 + tid);               // batch 5
    t49.x = fmaf(t49.x, wc, bc);
    t49.y = fmaf(t49.y, wc, bc);
    t49.z = fmaf(t49.z, wc, bc);
    t49.w = fmaf(t49.w, wc, bc);
    __builtin_nontemporal_store(t49, &yp[12288 + tid]);
}

extern "C" void kernel_launch(void* const* d_in, const int* in_sizes, int n_in,
                              void* d_out, int out_size, void* d_ws, size_t ws_size,
                              hipStream_t stream) {
    const float* x = (const float*)d_in[0];
    const float* w = (const float*)d_in[1];
    const float* b = (const float*)d_in[2];
    float* y = (float*)d_out;

    const int planes = 32 * 64;  // 2048 workgroups
    scale_kernel<<<planes, 256, 0, stream>>>(
        (const f32x4*)x, w, b, (f32x4*)y);
}